// Round 5
// baseline (476.319 us; speedup 1.0000x reference)
//
#include <hip/hip_runtime.h>
#include <hip/hip_fp16.h>
#include <type_traits>

// MultiHeadRelativeAttention (B=4, S=2048, H=8, dh=64, MAX_REL=96)
// K0a: proj = Q @ relk^T as f16 MFMA GEMM (M=65536, K=64, N=193) -> gproj f16
// K0b: Wo -> f16
// K1 : fused rel-pos flash attention, f16 MFMA, 2 wg/CU (75.5 KB LDS).
//      Pure-clip tile classification: ~22/32 k-tiles have ALL elements clipped to
//      bin 0 (or 192) for a wave's 16 q-rows (d-range per tile <=78 < 192), so
//      p = exp2(sc*c)*Crow -- no gathers/atomics/branches on those tiles.
// K2 : x @ Wo^T + bo (f16 MFMA)

#define SEQ   2048
#define NHEAD 8
#define DH    64
#define HID   512
#define ROWW  1536   // qkv row stride in floats (3*512)
#define QT    64
#define GPS   196    // gproj row stride (193 bins, padded)

#define C_L2E8 0.180336880111120f   // 0.125 * log2(e): softmax scale folded into exp2

typedef _Float16 h16;
typedef __attribute__((ext_vector_type(4))) float    f32x4;
typedef __attribute__((ext_vector_type(8))) _Float16 h16x8;
typedef __attribute__((ext_vector_type(4))) _Float16 h16x4;

static __device__ __forceinline__ h16x8 pack8(float4 a, float4 b) {
  h16x8 r;
  r[0]=(h16)a.x; r[1]=(h16)a.y; r[2]=(h16)a.z; r[3]=(h16)a.w;
  r[4]=(h16)b.x; r[5]=(h16)b.y; r[6]=(h16)b.z; r[7]=(h16)b.w;
  return r;
}

// LDS layouts (K1). K/Vt/P row strides = 72 h16 (144 B). Vt k-index carries a
// 3-bit XOR swizzle (granule 8 h16, bits 3-5) applied on BOTH write and read
// sides: spreads the 64-row staging writes across all 32 banks.
struct alignas(16) SmBase {
  float attnR[64][194];   // 49664 B  per-q-row bin accumulators
  h16   K[64][72];        //  9216 B  K tile [k][d]
  h16   Vt[64][72];       //  9216 B  V tile transposed [d][k^swz]
  h16   P[4][16][72];     //  9216 B  per-wave P staging (D->A layout)
};                        // 77312 B -> 2 wg/CU
struct alignas(16) SmFull {
  float attnR[64][194];
  h16   K[64][72];
  h16   Vt[64][72];
  h16   P[4][16][72];
  h16   projh[64][194];   // fallback path: proj in LDS, 1 wg/CU
};

// ---------------- K0a: proj = Q @ relk^T (MFMA) ----------------
__global__ __launch_bounds__(256)
void proj_gemm(const float* __restrict__ qkv, const float* __restrict__ relk,
               h16* __restrict__ gproj)
{
  const int qt = blockIdx.x, h = blockIdx.y, b = blockIdx.z;
  const int tid = (int)threadIdx.x;
  const int w = tid >> 6, l = tid & 63, l15 = l & 15, l4 = l >> 4;
  const int q0 = qt * 64;

  const float* qr = qkv + ((size_t)(b*SEQ) + q0 + w*16 + l15) * ROWW + h*DH + l4*8;
  h16x8 aq0 = pack8(*(const float4*)(qr),      *(const float4*)(qr + 4));
  h16x8 aq1 = pack8(*(const float4*)(qr + 32), *(const float4*)(qr + 36));

  h16* orow = gproj + ((size_t)(b*NHEAD + h)*SEQ + q0 + w*16) * GPS;

#pragma unroll
  for (int nt = 0; nt < 13; ++nt) {
    const int n0 = nt * 16;
    const int rc = (n0 + l15 > 192) ? 192 : n0 + l15;   // clamp tail tile
    const float* rkp = relk + rc*DH + l4*8;
    h16x8 b0 = pack8(*(const float4*)(rkp),      *(const float4*)(rkp + 4));
    h16x8 b1 = pack8(*(const float4*)(rkp + 32), *(const float4*)(rkp + 36));
    f32x4 z = {};
    z = __builtin_amdgcn_mfma_f32_16x16x32_f16(aq0, b0, z, 0, 0, 0);
    z = __builtin_amdgcn_mfma_f32_16x16x32_f16(aq1, b1, z, 0, 0, 0);
    if (n0 + l15 < GPS) {
#pragma unroll
      for (int j = 0; j < 4; ++j)
        orow[(size_t)(l4*4 + j)*GPS + n0 + l15] = (h16)z[j];
    }
  }
}

// ---------------- K0b: Wo -> f16 ----------------
__global__ __launch_bounds__(256)
void wo_convert(const float* __restrict__ Wo, h16* __restrict__ Woh)
{
  const size_t i = (size_t)blockIdx.x * 256 + threadIdx.x;
  float4 v = *(const float4*)(Wo + i*4);
  h16x4 o; o[0]=(h16)v.x; o[1]=(h16)v.y; o[2]=(h16)v.z; o[3]=(h16)v.w;
  *(h16x4*)(Woh + i*4) = o;
}

// ---------------- K1: fused relative attention ----------------
template<bool GP>
__global__ __launch_bounds__(256, 2)
void attn_fused(const float* __restrict__ qkv,
                const float* __restrict__ relk,
                const float* __restrict__ relv,
                const h16* __restrict__ gproj,
                h16* __restrict__ xout)
{
  using SM = typename std::conditional<GP, SmBase, SmFull>::type;
  __shared__ SM sm;

  // XCD-chunked swizzle: 1024 wgs, 8 XCDs, 128 contiguous work-ids per XCD.
  const int wg = (int)blockIdx.x;
  const int id = (wg & 7) * 128 + (wg >> 3);
  const int qt = id & 31, h = (id >> 5) & 7, b = id >> 8;

  const int tid = (int)threadIdx.x;
  const int w = tid >> 6, l = tid & 63, l15 = l & 15, l4 = l >> 4;
  const int q0 = qt * QT;
  const int dl = tid & 63, kq = tid >> 6;   // V-staging roles

  const float* qbase = qkv + ((size_t)(b*SEQ) + q0) * ROWW + h*DH;
  const float* kbase = qkv + (size_t)(b*SEQ) * ROWW + HID   + h*DH;
  const float* vbase = qkv + (size_t)(b*SEQ) * ROWW + 2*HID + h*DH;
  const h16* gprow = gproj + ((size_t)(b*NHEAD + h)*SEQ + q0 + w*16) * GPS;

  // zero bin accumulators
  {
    float4* az = (float4*)&sm.attnR[0][0];
    for (int i = tid; i < 64*194/4; i += 256) az[i] = (float4){0.f,0.f,0.f,0.f};
  }

  if constexpr (!GP) {
    const int prow = tid >> 2, psub = tid & 3;
    const float* qrow = qbase + (size_t)prow * ROWW;
    float4 qv[16];
#pragma unroll
    for (int c = 0; c < 16; ++c) qv[c] = *(const float4*)(qrow + c*4);
    for (int r = psub; r < 193; r += 4) {
      const float4* rk = (const float4*)(relk + r*DH);
      float acc = 0.f;
#pragma unroll
      for (int c = 0; c < 16; ++c) {
        float4 tt = rk[c];
        acc += qv[c].x*tt.x + qv[c].y*tt.y + qv[c].z*tt.z + qv[c].w*tt.w;
      }
      sm.projh[prow][r] = (h16)acc;
    }
  }

  // Q A-fragments: A[m=l15][k=l4*8+e]
  h16x8 aq0, aq1;
  {
    const float* qr = qbase + (size_t)(w*16 + l15) * ROWW + l4*8;
    aq0 = pack8(*(const float4*)(qr),      *(const float4*)(qr + 4));
    aq1 = pack8(*(const float4*)(qr + 32), *(const float4*)(qr + 36));
  }

  int rvq[4];
#pragma unroll
  for (int j = 0; j < 4; ++j) {
    int qg = q0 + w*16 + l4*4 + j;
    rvq[j] = (qg <= 1024) ? qg : (2048 - qg);
  }

  // wave-level rvq range (rv peaks at q=1024; min at range endpoints)
  const int qa = q0 + w*16, qb = qa + 15;
  const int rqa = (qa <= 1024) ? qa : 2048 - qa;
  const int rqb = (qb <= 1024) ? qb : 2048 - qb;
  const int rvqmin = rqa < rqb ? rqa : rqb;
  const int rvqmax = (qa <= 1024 && 1024 <= qb) ? 1024 : (rqa > rqb ? rqa : rqb);

  // tile class: 0 = all bins clip to 0, 2 = all clip to 192, 1 = mixed.
  // d-range per (wave,tile) <= 78 < 192, so "both clips in one tile" is impossible.
  auto classify = [&](int KT) -> int {
    const int ka = KT*64, kb = ka + 63;
    const int ra = (ka <= 1024) ? ka : 2048 - ka;
    const int rb = (kb <= 1024) ? kb : 2048 - kb;
    const int rmin = ra < rb ? ra : rb;
    const int rmax = (ka <= 1024 && 1024 <= kb) ? 1024 : (ra > rb ? ra : rb);
    if (rmax <= rvqmin - 96) return 0;
    if (rmin >= rvqmax + 96) return 2;
    return 1;
  };

  f32x4 acc[4] = {};
  float lsum[4] = {0.f,0.f,0.f,0.f};
  float c0[4]   = {0.f,0.f,0.f,0.f};
  float c192[4] = {0.f,0.f,0.f,0.f};

  float4 kreg[4];
  float  vreg[4][4];
  int    bins[4][4];
  float  pvf[4][4];

  auto kvIssue = [&](int KT) {
    const int kk = KT * 64;
#pragma unroll
    for (int m = 0; m < 4; ++m) {
      const int idx4 = tid + 256*m;
      kreg[m] = *(const float4*)(kbase + (size_t)(kk + (idx4>>4))*ROWW + (idx4&15)*4);
    }
#pragma unroll
    for (int m = 0; m < 4; ++m)
#pragma unroll
      for (int e = 0; e < 4; ++e)
        vreg[m][e] = vbase[(size_t)(kk + m*16 + kq*4 + e)*ROWW + dl];
  };

  auto kvWrite = [&]() {
#pragma unroll
    for (int m = 0; m < 4; ++m) {
      const int idx4 = tid + 256*m;
      const int kr = idx4 >> 4, c4 = idx4 & 15;
      h16x4 t; t[0]=(h16)kreg[m].x; t[1]=(h16)kreg[m].y; t[2]=(h16)kreg[m].z; t[3]=(h16)kreg[m].w;
      *(h16x4*)(&sm.K[kr][c4*4]) = t;
    }
    const int swz = ((dl >> 3) & 7) << 3;   // 3-bit k-XOR, granule 8 h16
#pragma unroll
    for (int m = 0; m < 4; ++m) {
      h16x4 u; u[0]=(h16)vreg[m][0]; u[1]=(h16)vreg[m][1]; u[2]=(h16)vreg[m][2]; u[3]=(h16)vreg[m][3];
      *(h16x4*)(&sm.Vt[dl][(m*16 + kq*4) ^ swz]) = u;
    }
  };

  // per-row clip-bin proj values (raw + exp2'd), rows l4*4+j
  float proj0f[4], proj192f[4], C0e[4], C192e[4];

  auto binGather = [&](int KT) {
#pragma unroll
    for (int ct = 0; ct < 4; ++ct) {
      const int kg = KT*64 + ct*16 + l15;
      const int rvk = (kg <= 1024) ? kg : (2048 - kg);
#pragma unroll
      for (int j = 0; j < 4; ++j) {
        int dd = rvk - rvq[j];
        dd = dd < -96 ? -96 : (dd > 96 ? 96 : dd);
        const int bin = dd + 96;
        bins[ct][j] = bin;
        if constexpr (GP) {
          if (bin > 0 && bin < 192)      // exec-masked gather, interior only (~1/3)
            pvf[ct][j] = (float)gprow[(size_t)(l4*4 + j)*GPS + bin];
          else
            pvf[ct][j] = (bin == 0) ? proj0f[j] : proj192f[j];
        }
      }
    }
  };

  // ---- prologue: tile 0 ----
  int cls = classify(0);
  kvIssue(0);
  kvWrite();
  __syncthreads();   // also covers projh writes (!GP) and attnR zeroing

  if constexpr (GP) {
#pragma unroll
    for (int j = 0; j < 4; ++j) {
      proj0f[j]   = (float)gprow[(size_t)(l4*4 + j)*GPS + 0];
      proj192f[j] = (float)gprow[(size_t)(l4*4 + j)*GPS + 192];
    }
  } else {
#pragma unroll
    for (int j = 0; j < 4; ++j) {
      proj0f[j]   = (float)sm.projh[w*16 + l4*4 + j][0];
      proj192f[j] = (float)sm.projh[w*16 + l4*4 + j][192];
    }
  }
#pragma unroll
  for (int j = 0; j < 4; ++j) {
    C0e[j]   = exp2f(proj0f[j]   * C_L2E8);
    C192e[j] = exp2f(proj192f[j] * C_L2E8);
  }
  if (cls == 1) binGather(0);

  for (int kt = 0; kt < 32; ++kt) {
    // QK^T: 16x64 per wave
    f32x4 sc[4];
#pragma unroll
    for (int ct = 0; ct < 4; ++ct) {
      h16x8 kb0 = *(const h16x8*)(&sm.K[ct*16 + l15][l4*8]);
      h16x8 kb1 = *(const h16x8*)(&sm.K[ct*16 + l15][32 + l4*8]);
      f32x4 z = {};
      z = __builtin_amdgcn_mfma_f32_16x16x32_f16(aq0, kb0, z, 0, 0, 0);
      z = __builtin_amdgcn_mfma_f32_16x16x32_f16(aq1, kb1, z, 0, 0, 0);
      sc[ct] = z;
    }

    if (kt < 31) kvIssue(kt + 1);    // prefetch next tile into regs

    // ---- middle: rel-pos add, exp, bin accumulation, P staging ----
    if (cls == 1) {
#pragma unroll
      for (int ct = 0; ct < 4; ++ct) {
#pragma unroll
        for (int j = 0; j < 4; ++j) {
          const int rowL = w*16 + l4*4 + j;
          const int bin = bins[ct][j];
          float pj;
          if constexpr (GP) pj = pvf[ct][j];
          else              pj = (float)sm.projh[rowL][bin];
          const float p = exp2f((sc[ct][j] + pj) * C_L2E8);
          lsum[j] += p;
          if (bin == 0)        c0[j]   += p;
          else if (bin == 192) c192[j] += p;
          else atomicAdd(&sm.attnR[rowL][bin], p);
          sm.P[w][l4*4 + j][ct*16 + l15] = (h16)p;
        }
      }
    } else if (cls == 0) {
#pragma unroll
      for (int ct = 0; ct < 4; ++ct) {
#pragma unroll
        for (int j = 0; j < 4; ++j) {
          const float p = exp2f(sc[ct][j] * C_L2E8) * C0e[j];
          lsum[j] += p;
          c0[j]   += p;
          sm.P[w][l4*4 + j][ct*16 + l15] = (h16)p;
        }
      }
    } else {
#pragma unroll
      for (int ct = 0; ct < 4; ++ct) {
#pragma unroll
        for (int j = 0; j < 4; ++j) {
          const float p = exp2f(sc[ct][j] * C_L2E8) * C192e[j];
          lsum[j] += p;
          c192[j] += p;
          sm.P[w][l4*4 + j][ct*16 + l15] = (h16)p;
        }
      }
    }

    if (kt < 31) {
      cls = classify(kt + 1);
      if (cls == 1) binGather(kt + 1);   // prefetch next proj gathers (mixed only)
    }

    // PV: acc += P V
    {
      h16x8 pa0 = *(const h16x8*)(&sm.P[w][l15][l4*8]);
      h16x8 pa1 = *(const h16x8*)(&sm.P[w][l15][32 + l4*8]);
#pragma unroll
      for (int vc = 0; vc < 4; ++vc) {
        const int d = vc*16 + l15;
        const int swr = ((d >> 3) & 7) << 3;
        h16x8 vb0 = *(const h16x8*)(&sm.Vt[d][(l4*8) ^ swr]);
        h16x8 vb1 = *(const h16x8*)(&sm.Vt[d][(32 + l4*8) ^ swr]);
        acc[vc] = __builtin_amdgcn_mfma_f32_16x16x32_f16(pa0, vb0, acc[vc], 0, 0, 0);
        acc[vc] = __builtin_amdgcn_mfma_f32_16x16x32_f16(pa1, vb1, acc[vc], 0, 0, 0);
      }
    }

    __syncthreads();                 // all waves done reading K/Vt
    if (kt < 31) kvWrite();          // restage next tile
    __syncthreads();                 // next tile ready
  }

  // ---- fold clip bins + lsum across the 16-lane row group ----
#pragma unroll
  for (int j = 0; j < 4; ++j) {
    for (int mask = 1; mask < 16; mask <<= 1) {
      c0[j]   += __shfl_xor(c0[j],   mask);
      c192[j] += __shfl_xor(c192[j], mask);
      lsum[j] += __shfl_xor(lsum[j], mask);
    }
  }
  if (l15 == 0) {
#pragma unroll
    for (int j = 0; j < 4; ++j) {
      atomicAdd(&sm.attnR[w*16 + l4*4 + j][0],   c0[j]);
      atomicAdd(&sm.attnR[w*16 + l4*4 + j][192], c192[j]);
    }
  }
  __syncthreads();

  // ---- w2 direct in D-layout ----
  float inv[4];
#pragma unroll
  for (int j = 0; j < 4; ++j) inv[j] = 1.f / lsum[j];
#pragma unroll 2
  for (int r = 0; r < 193; ++r) {
    float rvv[4], ar[4];
#pragma unroll
    for (int vc = 0; vc < 4; ++vc) rvv[vc] = relv[r*DH + vc*16 + l15];
#pragma unroll
    for (int j = 0; j < 4; ++j) ar[j] = sm.attnR[w*16 + l4*4 + j][r];
#pragma unroll
    for (int vc = 0; vc < 4; ++vc)
#pragma unroll
      for (int j = 0; j < 4; ++j)
        acc[vc][j] += ar[j] * rvv[vc];
  }

  // ---- normalize + store x (f16) ----
#pragma unroll
  for (int vc = 0; vc < 4; ++vc) {
#pragma unroll
    for (int j = 0; j < 4; ++j) {
      const int row16 = l4*4 + j;
      const int col   = vc*16 + l15;
      xout[((size_t)(b*SEQ) + q0 + w*16 + row16) * HID + h*DH + col] =
          (h16)(acc[vc][j] * inv[j]);
    }
  }
}

// ---------------- K2: out = x @ Wo^T + bo ----------------
template<bool WH>
__global__ __launch_bounds__(256)
void out_proj(const h16* __restrict__ xh,
              const float* __restrict__ Wo,
              const h16* __restrict__ Woh,
              const float* __restrict__ bo,
              float* __restrict__ out)
{
  const int tid = (int)threadIdx.x;
  const int w = tid >> 6, l = tid & 63, l15 = l & 15, l4 = l >> 4;
  const int m0 = blockIdx.x * 64 + w * 16;
  const int n0 = blockIdx.y * 64;
  f32x4 acc[4] = {};
  const h16* arow = xh + (size_t)(m0 + l15) * HID + l4*8;
#pragma unroll
  for (int ks = 0; ks < 16; ++ks) {
    h16x8 a = *(const h16x8*)(arow + ks*32);
#pragma unroll
    for (int ct = 0; ct < 4; ++ct) {
      h16x8 bfrag;
      if constexpr (WH) {
        bfrag = *(const h16x8*)(Woh + (size_t)(n0 + ct*16 + l15) * HID + ks*32 + l4*8);
      } else {
        const float* wrow = Wo + (size_t)(n0 + ct*16 + l15) * HID + ks*32 + l4*8;
        bfrag = pack8(*(const float4*)wrow, *(const float4*)(wrow + 4));
      }
      acc[ct] = __builtin_amdgcn_mfma_f32_16x16x32_f16(a, bfrag, acc[ct], 0, 0, 0);
    }
  }
#pragma unroll
  for (int ct = 0; ct < 4; ++ct) {
    const int col = n0 + ct*16 + l15;
    const float bv = bo[col];
#pragma unroll
    for (int j = 0; j < 4; ++j)
      out[(size_t)(m0 + l4*4 + j) * HID + col] = acc[ct][j] + bv;
  }
}

extern "C" void kernel_launch(void* const* d_in, const int* in_sizes, int n_in,
                              void* d_out, int out_size, void* d_ws, size_t ws_size,
                              hipStream_t stream)
{
  const float* qkv  = (const float*)d_in[0];
  const float* relk = (const float*)d_in[1];
  const float* relv = (const float*)d_in[2];
  const float* Wo   = (const float*)d_in[3];
  const float* bo   = (const float*)d_in[4];
  float* out = (float*)d_out;

  const size_t off_gproj = (size_t)4*SEQ*HID*2;                       //  8.39 MB (xh)
  const size_t off_woh   = off_gproj + (size_t)4*NHEAD*SEQ*GPS*2;     // +25.69 MB (gproj)
  const size_t need      = off_woh + (size_t)HID*HID*2;               // +0.52 MB (Woh)

  h16* xh = (h16*)d_ws;

  if (ws_size >= need) {
    h16* gproj = (h16*)((char*)d_ws + off_gproj);
    h16* woh   = (h16*)((char*)d_ws + off_woh);
    proj_gemm<<<dim3(SEQ/64, NHEAD, 4), 256, 0, stream>>>(qkv, relk, gproj);
    wo_convert<<<dim3(HID*HID/4/256), 256, 0, stream>>>(Wo, woh);
    attn_fused<true><<<dim3(1024), 256, 0, stream>>>(qkv, relk, relv, gproj, xh);
    out_proj<true><<<dim3((4*SEQ)/64, HID/64), 256, 0, stream>>>(xh, Wo, woh, bo, out);
  } else {
    attn_fused<false><<<dim3(1024), 256, 0, stream>>>(qkv, relk, relv, nullptr, xh);
    out_proj<false><<<dim3((4*SEQ)/64, HID/64), 256, 0, stream>>>(xh, Wo, nullptr, bo, out);
  }
}